// Round 3
// baseline (259.429 us; speedup 1.0000x reference)
//
#include <hip/hip_runtime.h>
#include <hip/hip_cooperative_groups.h>
#include <math.h>

namespace cg = cooperative_groups;

#define N_F   128
#define N_D   2048
#define BATCH 8
#define ALPHA 0.2f

// ws layout (floats):
//   [0   .. 127]  sq_orig[i]  = ||positions_orig[i]||^2
//   [128 .. 255]  sq_final[i] = ||pos_final[i]||^2 (atomic-accumulated)
//   [512 ..]      pos_final rows (128 x 2048)
#define WS_SQO   0
#define WS_SQF   128
#define WS_POSF  512

__global__ void __launch_bounds__(256, 1)
ff_fused(const float* __restrict__ pos,
         const float* __restrict__ noise,
         const float* __restrict__ best_intensity,
         const float* __restrict__ best_position,
         float* __restrict__ ws,
         float* __restrict__ out) {
    cg::grid_group grid = cg::this_grid();
    const int bid  = blockIdx.x;   // 256 blocks
    const int tid  = threadIdx.x;  // 256 threads
    const int wave = tid >> 6;
    const int lane = tid & 63;

    __shared__ float s_red[256];
    __shared__ float s_sq[N_F];
    __shared__ unsigned char s_list[N_F];
    __shared__ unsigned long long s_mask[2];
    __shared__ float sv[N_F];
    __shared__ int   sidx[N_F];

    // ---- P1: blocks 0..127 compute ||positions[i]||^2, zero sq_final ----
    if (bid < N_F) {
        const float* row = pos + (size_t)bid * N_D;
        float4 a = *(const float4*)(row + tid * 4);
        float4 b = *(const float4*)(row + 1024 + tid * 4);
        float ss = a.x*a.x + a.y*a.y + a.z*a.z + a.w*a.w
                 + b.x*b.x + b.y*b.y + b.z*b.z + b.w*b.w;
        s_red[tid] = ss;
        __syncthreads();
        for (int s = 128; s > 0; s >>= 1) {
            if (tid < s) s_red[tid] += s_red[tid + s];
            __syncthreads();
        }
        if (tid == 0) {
            ws[WS_SQO + bid] = s_red[0];
            ws[WS_SQF + bid] = 0.0f;
        }
    }
    grid.sync();

    // ---- P2: block (i, c): pos_final[i] = pos[i] + ALPHA * sum(accepted noise rows) ----
    const int i = bid & (N_F - 1);
    const int c = bid >> 7;
    if (tid < N_F) s_sq[tid] = ws[WS_SQO + tid];
    __syncthreads();
    const float si = s_sq[i];
    const bool cond = (tid < N_F) && (tid != i) && (s_sq[tid] < si);
    const unsigned long long m = __ballot(cond);
    if (wave < 2 && lane == 0) s_mask[wave] = m;
    __syncthreads();
    const int total0 = __popcll(s_mask[0]);
    const int nacc   = total0 + __popcll(s_mask[1]);
    const int npad   = (nacc + 7) & ~7;          // pad to full unroll-8 batches
    if (cond) {
        int p = __popcll(m & ((1ULL << lane) - 1ULL)) + (wave == 1 ? total0 : 0);
        s_list[p] = (unsigned char)tid;
    }
    if (tid >= nacc && tid < npad) s_list[tid] = 0;  // dummy rows, weight 0
    __syncthreads();

    const int d0 = c * 1024 + tid * 4;
    const float* nbase = noise + (size_t)i * (N_F * N_D) + d0;

    float4 acc = make_float4(0.f, 0.f, 0.f, 0.f);
    for (int t = 0; t < npad; t += 8) {
        #pragma unroll
        for (int u = 0; u < 8; ++u) {
            const int idx = t + u;
            const float4 v = *(const float4*)(nbase + (size_t)s_list[idx] * N_D);
            const float w = (idx < nacc) ? 1.0f : 0.0f;
            acc.x = fmaf(w, v.x, acc.x);
            acc.y = fmaf(w, v.y, acc.y);
            acc.z = fmaf(w, v.z, acc.z);
            acc.w = fmaf(w, v.w, acc.w);
        }
    }

    const float4 p = *(const float4*)(pos + (size_t)i * N_D + d0);
    float4 pf;
    pf.x = fmaf(ALPHA, acc.x, p.x);
    pf.y = fmaf(ALPHA, acc.y, p.y);
    pf.z = fmaf(ALPHA, acc.z, p.z);
    pf.w = fmaf(ALPHA, acc.w, p.w);
    *(float4*)(ws + WS_POSF + (size_t)i * N_D + d0) = pf;

    float ss2 = pf.x*pf.x + pf.y*pf.y + pf.z*pf.z + pf.w*pf.w;
    s_red[tid] = ss2;
    __syncthreads();
    for (int s = 128; s > 0; s >>= 1) {
        if (tid < s) s_red[tid] += s_red[tid + s];
        __syncthreads();
    }
    if (tid == 0) atomicAdd(&ws[WS_SQF + i], s_red[0]);
    grid.sync();

    // ---- P3: blocks 0..15 redundantly argmin, then write output slice ----
    if (bid < 16) {
        if (tid < N_F) { sv[tid] = ws[WS_SQF + tid]; sidx[tid] = tid; }
        __syncthreads();
        for (int s = 64; s > 0; s >>= 1) {
            if (tid < s) {
                float v2 = sv[tid + s];
                int   i2 = sidx[tid + s];
                if (v2 < sv[tid] || (v2 == sv[tid] && i2 < sidx[tid])) {
                    sv[tid] = v2; sidx[tid] = i2;
                }
            }
            __syncthreads();
        }
        const int  best   = sidx[0];
        const bool better = sqrtf(sv[0]) < best_intensity[0];
        const float* src  = better ? (ws + WS_POSF + (size_t)best * N_D)
                                   : best_position;
        const int t = bid * 256 + tid;           // 0..4095 float4 slots
        const int d = (t << 2) & (N_D - 1);
        float4 v = *(const float4*)(src + d);
        *(float4*)(out + (size_t)t * 4) = v;
    }
}

extern "C" void kernel_launch(void* const* d_in, const int* in_sizes, int n_in,
                              void* d_out, int out_size, void* d_ws, size_t ws_size,
                              hipStream_t stream) {
    const float* positions      = (const float*)d_in[1];
    const float* noise          = (const float*)d_in[2];
    const float* best_position  = (const float*)d_in[3];
    const float* best_intensity = (const float*)d_in[4];
    float* ws  = (float*)d_ws;
    float* out = (float*)d_out;

    void* args[] = { (void*)&positions, (void*)&noise, (void*)&best_intensity,
                     (void*)&best_position, (void*)&ws, (void*)&out };
    hipLaunchCooperativeKernel((void*)ff_fused, dim3(256), dim3(256),
                               args, 0, stream);
}

// Round 4
// 201.596 us; speedup vs baseline: 1.2869x; 1.2869x over previous
//
#include <hip/hip_runtime.h>
#include <math.h>

#define N_F   128
#define N_D   2048
#define BATCH 8
#define ALPHA 0.2f
#define NJC   8     // j-slices per firefly
#define JSL   16    // j's per slice

// ws layout (floats):
//   [0   .. 127]   sq_orig[i]
//   [128 .. 255]   sq_final[i]
//   [512 ..]       partial sums: [i][jc][N_D]  (128*8*2048 = 8 MB)
//   [512 + 128*8*2048 ..] pos_final rows (128 x 2048)
#define WS_SQO   0
#define WS_SQF   128
#define WS_PART  512
#define WS_POSF  (512 + N_F * NJC * N_D)

// K1: per-firefly squared norm of original positions.
__global__ void ff_k1_norms(const float* __restrict__ pos, float* __restrict__ ws) {
    const int i   = blockIdx.x;
    const int tid = threadIdx.x;            // 256 threads
    const float* row = pos + (size_t)i * N_D;
    float4 a = *(const float4*)(row + tid * 4);
    float4 b = *(const float4*)(row + 1024 + tid * 4);
    float ss = a.x*a.x + a.y*a.y + a.z*a.z + a.w*a.w
             + b.x*b.x + b.y*b.y + b.z*b.z + b.w*b.w;
    __shared__ float red[256];
    red[tid] = ss;
    __syncthreads();
    for (int s = 128; s > 0; s >>= 1) {
        if (tid < s) red[tid] += red[tid + s];
        __syncthreads();
    }
    if (tid == 0) ws[WS_SQO + i] = red[0];
}

// K2: block (i, jc, c) sums accepted noise rows j in [jc*16, jc*16+16)
// over dim chunk c (1024 floats), writes deterministic partial to ws.
// 2048 blocks x 256 threads -> 8 blocks/CU, full 32 waves/CU occupancy.
__global__ void ff_k2_partial(const float* __restrict__ noise,
                              float* __restrict__ ws) {
    const int i    = blockIdx.x;
    const int jc   = blockIdx.y;
    const int c    = blockIdx.z;
    const int tid  = threadIdx.x;
    const int wave = tid >> 6;
    const int lane = tid & 63;

    __shared__ float s_sq[N_F];
    __shared__ unsigned char s_list[JSL];
    __shared__ int s_n;

    if (tid < N_F) s_sq[tid] = ws[WS_SQO + tid];
    __syncthreads();
    const float si = s_sq[i];
    if (wave == 0) {
        const int j = jc * JSL + lane;          // lanes 0..15 valid
        const bool cond = (lane < JSL) && (j != i) && (s_sq[j] < si);
        const unsigned long long m = __ballot(cond);
        if (cond) {
            int p = __popcll(m & ((1ULL << lane) - 1ULL));
            s_list[p] = (unsigned char)j;
        }
        if (lane == 0) s_n = __popcll(m);
    }
    __syncthreads();
    const int nacc = s_n;

    const int d0 = c * 1024 + tid * 4;
    const float* nbase = noise + (size_t)i * (N_F * N_D) + d0;

    float4 acc = make_float4(0.f, 0.f, 0.f, 0.f);
    for (int t = 0; t < nacc; ++t) {
        const float4 v = *(const float4*)(nbase + (size_t)s_list[t] * N_D);
        acc.x += v.x; acc.y += v.y; acc.z += v.z; acc.w += v.w;
    }
    *(float4*)(ws + WS_PART + ((size_t)(i * NJC + jc)) * N_D + d0) = acc;
}

// K3: fold 8 partials + positions -> pos_final + ||pos_final||^2.
__global__ void ff_k3_fold(const float* __restrict__ pos, float* __restrict__ ws) {
    const int i   = blockIdx.x;
    const int tid = threadIdx.x;            // 256 threads, 2 float4 slots each
    float ss = 0.0f;
    #pragma unroll
    for (int h = 0; h < 2; ++h) {
        const int d = h * 1024 + tid * 4;
        float4 acc = make_float4(0.f, 0.f, 0.f, 0.f);
        #pragma unroll
        for (int jc = 0; jc < NJC; ++jc) {
            const float4 v = *(const float4*)(ws + WS_PART +
                                ((size_t)(i * NJC + jc)) * N_D + d);
            acc.x += v.x; acc.y += v.y; acc.z += v.z; acc.w += v.w;
        }
        const float4 p = *(const float4*)(pos + (size_t)i * N_D + d);
        float4 pf;
        pf.x = fmaf(ALPHA, acc.x, p.x);
        pf.y = fmaf(ALPHA, acc.y, p.y);
        pf.z = fmaf(ALPHA, acc.z, p.z);
        pf.w = fmaf(ALPHA, acc.w, p.w);
        *(float4*)(ws + WS_POSF + (size_t)i * N_D + d) = pf;
        ss += pf.x*pf.x + pf.y*pf.y + pf.z*pf.z + pf.w*pf.w;
    }
    __shared__ float red[256];
    red[tid] = ss;
    __syncthreads();
    for (int s = 128; s > 0; s >>= 1) {
        if (tid < s) red[tid] += red[tid + s];
        __syncthreads();
    }
    if (tid == 0) ws[WS_SQF + i] = red[0];
}

// K4: argmin over sq_final (first-index tie-break) + broadcast to (BATCH, N_D).
__global__ void ff_k4_out(const float* __restrict__ best_intensity,
                          const float* __restrict__ best_position,
                          const float* __restrict__ ws,
                          float* __restrict__ out) {
    const int tid = threadIdx.x;            // 256 threads, 16 blocks
    __shared__ float sv[N_F];
    __shared__ int   sidx[N_F];
    if (tid < N_F) { sv[tid] = ws[WS_SQF + tid]; sidx[tid] = tid; }
    __syncthreads();
    for (int s = 64; s > 0; s >>= 1) {
        if (tid < s) {
            float v2 = sv[tid + s];
            int   i2 = sidx[tid + s];
            if (v2 < sv[tid] || (v2 == sv[tid] && i2 < sidx[tid])) {
                sv[tid] = v2; sidx[tid] = i2;
            }
        }
        __syncthreads();
    }
    const int  best   = sidx[0];
    const bool better = sqrtf(sv[0]) < best_intensity[0];
    const float* src  = better ? (ws + WS_POSF + (size_t)best * N_D)
                               : best_position;
    const int t = blockIdx.x * 256 + tid;   // 0..4095 float4 slots
    const int d = (t << 2) & (N_D - 1);
    float4 v = *(const float4*)(src + d);
    *(float4*)(out + (size_t)t * 4) = v;
}

extern "C" void kernel_launch(void* const* d_in, const int* in_sizes, int n_in,
                              void* d_out, int out_size, void* d_ws, size_t ws_size,
                              hipStream_t stream) {
    const float* positions      = (const float*)d_in[1];
    const float* noise          = (const float*)d_in[2];
    const float* best_position  = (const float*)d_in[3];
    const float* best_intensity = (const float*)d_in[4];
    float* ws  = (float*)d_ws;
    float* out = (float*)d_out;

    ff_k1_norms<<<N_F, 256, 0, stream>>>(positions, ws);
    dim3 g2(N_F, NJC, 2);
    ff_k2_partial<<<g2, 256, 0, stream>>>(noise, ws);
    ff_k3_fold<<<N_F, 256, 0, stream>>>(positions, ws);
    ff_k4_out<<<16, 256, 0, stream>>>(best_intensity, best_position, ws, out);
}